// Round 7
// baseline (216.663 us; speedup 1.0000x reference)
//
#include <hip/hip_runtime.h>
#include <math.h>

constexpr int B = 2, C = 16, H = 128, W = 128;
constexpr int HW = H * W;

// xpad: [B,16,146,148]; orig (h,w) -> (h+9, w+9); zero pads elsewhere
constexpr int XR = 146, XS = 148, XCH = XR * XS;
constexpr size_t XPAD_ELEMS = (size_t)B * C * XCH;          // 691,456

// ypad: [B,16,130,136]; orig (h,w) -> (h+1, w+4); zero pads elsewhere
constexpr int YR = 130, YS = 136, YCH = YR * YS;
constexpr size_t YPAD_ELEMS = (size_t)B * C * YCH;          // 565,760

__device__ __forceinline__ float4 ld4(const float* p) { return *(const float4*)p; }

// ===========================================================================
// Kernel 2: per-pixel 19x19 conv. Plain-HIP loads, two-row double buffer,
// sched_barrier(0) phase fences. waves_per_eu(2,2) caps occupancy at 2
// waves/SIMD -> 256-VGPR budget so the ~220-VGPR live batch is legal and the
// scheduler has no occupancy incentive to sink the loads.
// Thread = 4 px x 1 ch, all 19 rows. Block = 8wq x 16c = 128 thr (32px,16ch).
// Grid = wb4 x h128 x b2 = 1024 blocks = 4/CU -> 8 waves/CU, single pass.
// ===========================================================================
#define KPN_LOAD(KBUF, XBUF, kh_)                                            \
  {                                                                          \
    const float* kp_ = kb + (size_t)((kh_) * 19) * HW;                       \
    _Pragma("unroll")                                                        \
    for (int kw_ = 0; kw_ < 19; ++kw_)                                       \
      KBUF[kw_] = ld4(kp_ + (size_t)kw_ * HW);                               \
    const float* xr_ = xb + (size_t)(kh_) * XS;                              \
    _Pragma("unroll")                                                        \
    for (int j_ = 0; j_ < 6; ++j_)                                           \
      XBUF[j_] = ld4(xr_ + 4 * j_);                                          \
  }                                                                          \
  __builtin_amdgcn_sched_barrier(0);

#define XCOMP(XB, I)                                                         \
  (((I) & 3) == 0 ? XB[(I) >> 2].x : ((I) & 3) == 1 ? XB[(I) >> 2].y         \
   : ((I) & 3) == 2 ? XB[(I) >> 2].z : XB[(I) >> 2].w)

#define KPN_COMP(KBUF, XBUF)                                                 \
  {                                                                          \
    _Pragma("unroll")                                                        \
    for (int kw_ = 0; kw_ < 19; ++kw_) {                                     \
      acc.x = fmaf(XCOMP(XBUF, kw_ + 0), KBUF[kw_].x, acc.x);                \
      acc.y = fmaf(XCOMP(XBUF, kw_ + 1), KBUF[kw_].y, acc.y);                \
      acc.z = fmaf(XCOMP(XBUF, kw_ + 2), KBUF[kw_].z, acc.z);                \
      acc.w = fmaf(XCOMP(XBUF, kw_ + 3), KBUF[kw_].w, acc.w);                \
    }                                                                        \
  }                                                                          \
  __builtin_amdgcn_sched_barrier(0);

__global__ __launch_bounds__(128) __attribute__((amdgpu_waves_per_eu(2, 2)))
void kpn19(const float* __restrict__ xpad,   // [B,16,146,148]
           const float* __restrict__ kern,   // [B,361,128,128]
           float* __restrict__ ypad)         // [B,16,130,136]
{
    int wq = threadIdx.x & 7;
    int c  = threadIdx.x >> 3;       // 0..15
    int blk = blockIdx.x;            // 1024 = wb4 x h128 x b2
    int wb = blk & 3;
    int h  = (blk >> 2) & 127;
    int b  = blk >> 9;
    int w0 = wb * 32 + wq * 4;

    const float* kb = kern + (size_t)b * 361 * HW + (size_t)h * W + w0;
    const float* xb = xpad + (size_t)(b * C + c) * XCH + (size_t)h * XS + w0;

    float4 KA[19], KB[19], XA[6], XB[6];
    float4 acc = make_float4(0.f, 0.f, 0.f, 0.f);

    KPN_LOAD(KA, XA, 0);
    for (int rr = 0; rr < 9; ++rr) {
        KPN_LOAD(KB, XB, 2 * rr + 1);
        KPN_COMP(KA, XA);                // compiler waits (counted) on KA/XA
        KPN_LOAD(KA, XA, 2 * rr + 2);
        KPN_COMP(KB, XB);
    }
    KPN_COMP(KA, XA);                    // row 18

    float* yp = ypad + ((size_t)(b * C + c) * YR + (h + 1)) * YS + (w0 + 4);
    *(float4*)yp = acc;
}

// ===========================================================================
// Kernel 1: 3x3 conv (pad 1) + exact GELU -> xpad.
// Thread = 1 px x 4 oc; ic processed in 4-ic batches (36 taps in flight),
// ping-pong with fences. Border taps predicated to zero.
// Block = 128 px x 2 og; grid = gg2 x h128 x b2 = 512 -> 8 waves/CU.
// ===========================================================================
#define C1_LOAD(BUF, ic0_)                                                   \
  {                                                                          \
    _Pragma("unroll")                                                        \
    for (int i_ = 0; i_ < 4; ++i_) {                                         \
      const float* p_ = inb + (size_t)((ic0_) + i_) * HW + (size_t)h * W + px;\
      BUF[i_ * 9 + 0] = (hm && wm) ? p_[-W - 1] : 0.f;                       \
      BUF[i_ * 9 + 1] = hm         ? p_[-W]     : 0.f;                       \
      BUF[i_ * 9 + 2] = (hm && wp) ? p_[-W + 1] : 0.f;                       \
      BUF[i_ * 9 + 3] = wm         ? p_[-1]     : 0.f;                       \
      BUF[i_ * 9 + 4] =              p_[0];                                  \
      BUF[i_ * 9 + 5] = wp         ? p_[1]      : 0.f;                       \
      BUF[i_ * 9 + 6] = (hp && wm) ? p_[W - 1]  : 0.f;                       \
      BUF[i_ * 9 + 7] = hp         ? p_[W]      : 0.f;                       \
      BUF[i_ * 9 + 8] = (hp && wp) ? p_[W + 1]  : 0.f;                       \
    }                                                                        \
  }                                                                          \
  __builtin_amdgcn_sched_barrier(0);

#define CX_COMP(BUF, ic0_)                                                   \
  {                                                                          \
    _Pragma("unroll")                                                        \
    for (int i_ = 0; i_ < 4; ++i_) {                                         \
      const float* t_ = BUF + i_ * 9;                                        \
      _Pragma("unroll")                                                      \
      for (int j_ = 0; j_ < 4; ++j_) {                                       \
        const float* wp_ = ws + (oc0 + j_) * 144 + ((ic0_) + i_) * 9;        \
        float s_ = fmaf(wp_[0], t_[0], fmaf(wp_[1], t_[1], fmaf(wp_[2], t_[2],\
                   fmaf(wp_[3], t_[3], fmaf(wp_[4], t_[4], fmaf(wp_[5], t_[5],\
                   fmaf(wp_[6], t_[6], fmaf(wp_[7], t_[7], wp_[8] * t_[8]))))))));\
        if (j_ == 0) a0 += s_; else if (j_ == 1) a1 += s_;                   \
        else if (j_ == 2) a2 += s_; else a3 += s_;                           \
      }                                                                      \
    }                                                                        \
  }                                                                          \
  __builtin_amdgcn_sched_barrier(0);

__global__ __launch_bounds__(256) __attribute__((amdgpu_waves_per_eu(2, 2)))
void conv1_gelu(const float* __restrict__ in, const float* __restrict__ w1,
                const float* __restrict__ b1, float* __restrict__ xpad)
{
    __shared__ float ws[2304];
    __shared__ float bs[16];
    for (int i = threadIdx.x; i < 2304; i += 256) ws[i] = w1[i];
    if (threadIdx.x < 16) bs[threadIdx.x] = b1[threadIdx.x];
    __syncthreads();

    int px = threadIdx.x & 127;
    int og = threadIdx.x >> 7;           // wave-uniform
    int blk = blockIdx.x;                // 512 = gg2 x h128 x b2
    int gg = blk & 1;
    int h  = (blk >> 1) & 127;
    int b  = blk >> 8;
    int oc0 = (gg * 2 + og) * 4;

    const float* inb = in + (size_t)b * C * HW;
    bool hm = (h > 0), hp = (h < 127), wm = (px > 0), wp = (px < 127);

    float a0 = 0.f, a1 = 0.f, a2 = 0.f, a3 = 0.f;
    float TA[36], TB[36];

    C1_LOAD(TA, 0);
    C1_LOAD(TB, 4);
    CX_COMP(TA, 0);
    C1_LOAD(TA, 8);
    CX_COMP(TB, 4);
    C1_LOAD(TB, 12);
    CX_COMP(TA, 8);
    CX_COMP(TB, 12);

    float* xp = xpad + ((size_t)(b * C + oc0) * XR + (h + 9)) * XS + (px + 9);
    float v;
    v = a0 + bs[oc0 + 0]; xp[0]       = 0.5f * v * (1.0f + erff(v * 0.70710678f));
    v = a1 + bs[oc0 + 1]; xp[XCH]     = 0.5f * v * (1.0f + erff(v * 0.70710678f));
    v = a2 + bs[oc0 + 2]; xp[2 * XCH] = 0.5f * v * (1.0f + erff(v * 0.70710678f));
    v = a3 + bs[oc0 + 3]; xp[3 * XCH] = 0.5f * v * (1.0f + erff(v * 0.70710678f));
}

// ===========================================================================
// Kernel 3: 3x3 conv (pad 1) + sigmoid -> out. Same structure; reads padded
// y so all taps are unconditional.
// ===========================================================================
#define C2_LOAD(BUF, ic0_)                                                   \
  {                                                                          \
    _Pragma("unroll")                                                        \
    for (int i_ = 0; i_ < 4; ++i_) {                                         \
      const float* p_ = ybase + (size_t)((ic0_) + i_) * YCH;                 \
      BUF[i_ * 9 + 0] = p_[-YS - 1]; BUF[i_ * 9 + 1] = p_[-YS];              \
      BUF[i_ * 9 + 2] = p_[-YS + 1]; BUF[i_ * 9 + 3] = p_[-1];               \
      BUF[i_ * 9 + 4] = p_[0];       BUF[i_ * 9 + 5] = p_[1];                \
      BUF[i_ * 9 + 6] = p_[YS - 1];  BUF[i_ * 9 + 7] = p_[YS];               \
      BUF[i_ * 9 + 8] = p_[YS + 1];                                          \
    }                                                                        \
  }                                                                          \
  __builtin_amdgcn_sched_barrier(0);

__global__ __launch_bounds__(256) __attribute__((amdgpu_waves_per_eu(2, 2)))
void conv2_sig(const float* __restrict__ ypad, const float* __restrict__ w2,
               const float* __restrict__ b2, float* __restrict__ out)
{
    __shared__ float ws[2304];
    __shared__ float bs[16];
    for (int i = threadIdx.x; i < 2304; i += 256) ws[i] = w2[i];
    if (threadIdx.x < 16) bs[threadIdx.x] = b2[threadIdx.x];
    __syncthreads();

    int px = threadIdx.x & 127;
    int og = threadIdx.x >> 7;
    int blk = blockIdx.x;
    int gg = blk & 1;
    int h  = (blk >> 1) & 127;
    int b  = blk >> 8;
    int oc0 = (gg * 2 + og) * 4;

    // center of 3x3 window in padded coords for channel 0
    const float* ybase = ypad + ((size_t)(b * C) * YR + (h + 1)) * YS + (px + 4);

    float a0 = 0.f, a1 = 0.f, a2 = 0.f, a3 = 0.f;
    float TA[36], TB[36];

    C2_LOAD(TA, 0);
    C2_LOAD(TB, 4);
    CX_COMP(TA, 0);
    C2_LOAD(TA, 8);
    CX_COMP(TB, 4);
    C2_LOAD(TB, 12);
    CX_COMP(TA, 8);
    CX_COMP(TB, 12);

    float* op = out + ((size_t)(b * C + oc0) * H + h) * W + px;
    float v;
    v = a0 + bs[oc0 + 0]; op[0]      = 1.0f / (1.0f + expf(-v));
    v = a1 + bs[oc0 + 1]; op[HW]     = 1.0f / (1.0f + expf(-v));
    v = a2 + bs[oc0 + 2]; op[2 * HW] = 1.0f / (1.0f + expf(-v));
    v = a3 + bs[oc0 + 3]; op[3 * HW] = 1.0f / (1.0f + expf(-v));
}

// ---------------------------------------------------------------------------
extern "C" void kernel_launch(void* const* d_in, const int* in_sizes, int n_in,
                              void* d_out, int out_size, void* d_ws, size_t ws_size,
                              hipStream_t stream)
{
    const float* input  = (const float*)d_in[0];
    const float* kernel = (const float*)d_in[1];
    const float* w1     = (const float*)d_in[2];
    const float* b1     = (const float*)d_in[3];
    const float* w2     = (const float*)d_in[4];
    const float* b2     = (const float*)d_in[5];
    float* out = (float*)d_out;

    float* xpad = (float*)d_ws;
    float* ypad = xpad + XPAD_ELEMS;

    hipMemsetAsync(d_ws, 0, (XPAD_ELEMS + YPAD_ELEMS) * sizeof(float), stream);

    conv1_gelu<<<512, 256, 0, stream>>>(input, w1, b1, xpad);
    kpn19<<<1024, 128, 0, stream>>>(xpad, kernel, ypad);
    conv2_sig<<<512, 256, 0, stream>>>(ypad, w2, b2, out);
}

// Round 8
// 75.081 us; speedup vs baseline: 2.8857x; 2.8857x over previous
//
#include <hip/hip_runtime.h>
#include <math.h>

constexpr int B = 2, C = 16, H = 128, W = 128;
constexpr int HW = H * W;

// xpad: [B,16,146,148]; orig (h,w) -> (h+9, w+9); zero pads elsewhere
constexpr int XR = 146, XS = 148, XCH = XR * XS;
constexpr size_t XPAD_ELEMS = (size_t)B * C * XCH;          // 691,456

// ypad: [B,16,130,136]; orig (h,w) -> (h+1, w+4); zero pads elsewhere
constexpr int YR = 130, YS = 136, YCH = YR * YS;
constexpr size_t YPAD_ELEMS = (size_t)B * C * YCH;          // 565,760

__device__ __forceinline__ float4 ld4(const float* p) { return *(const float4*)p; }

// ===========================================================================
// kpn19: per-pixel 19x19 conv as an async global_load_lds pipeline (T3+T4).
// Block = 256 thr = 16 px-quads (64 px) x 16 ch. Grid = wb2 x h128 x b2 = 512
// (2 blocks/CU, 8 waves/CU). LDS ring of 4 slots, one slot per kh-step:
//   slot floats [0,1216)        kern[kw 0..18][px 0..63]
//   slot floats [1216, 3072)    x[c 0..15][col 0..115]  (cols w0..w0+115 padded)
// Stage = 768 float4 = 3 global_load_lds_dwordx4 per wave (branchless select
// -> wave-uniform instr count, so counted vmcnt is sound).
// Per step: vmcnt(6) [2 steps still in flight] -> s_barrier -> stage kh+3
// (slot freed by previous step, barrier guarantees all waves done) -> compute.
// ===========================================================================
constexpr int SLOT_F = 3072;           // floats per slot (12 KB)
constexpr int XOFF = 1216;

__global__ __launch_bounds__(256) void kpn19(
    const float* __restrict__ xpad,  // [B,16,146,148]
    const float* __restrict__ kern,  // [B,361,128,128]
    float* __restrict__ ypad)        // [B,16,130,136]
{
    __shared__ __align__(16) float slots[4][SLOT_F];   // 48 KB

    int tid = threadIdx.x;
    int pq  = tid & 15;
    int c   = tid >> 4;
    int blk = blockIdx.x;            // 512 = wb2 x h128 x b2
    int wb  = blk & 1;
    int h   = (blk >> 1) & 127;
    int b   = blk >> 8;
    int w0  = wb * 64;
    int px0 = pq * 4;

    const float* kbg = kern + (size_t)b * 361 * HW + (size_t)h * W + w0;
    const float* xbg = xpad + (size_t)b * C * XCH + w0;

    // Precompute per-j staging sources (f = tid + j*256; invariant parts).
    // f < 304: kern plane p=f>>4, chunk q=f&15 -> src = kbg + (khs*19+p)*HW + 4q
    // f >=304: g=f-304, c'=g/29, col4=g%29 -> src = xbg + c'*XCH + (h+khs)*XS + 4*col4
    const float* kA[3];
    const float* xB[3];
    bool isK[3];
    #pragma unroll
    for (int j = 0; j < 3; ++j) {
        int f = tid + j * 256;
        isK[j] = (f < 304);
        int p = f >> 4, q = f & 15;
        kA[j] = kbg + (size_t)p * HW + (q << 2);
        int g = isK[j] ? 0 : (f - 304);
        int cc = g / 29, col4 = g % 29;
        xB[j] = xbg + (size_t)cc * XCH + (size_t)h * XS + (col4 << 2);
    }
    int wid = tid >> 6;              // wave id, uniform

    auto STAGE = [&](int khs, int s) {
        #pragma unroll
        for (int j = 0; j < 3; ++j) {
            const float* srcK = kA[j] + (size_t)khs * 19 * HW;
            const float* srcX = xB[j] + (size_t)khs * XS;
            const float* src  = isK[j] ? srcK : srcX;
            __builtin_amdgcn_global_load_lds(
                (const float*)src,
                &slots[s][(j * 256 + wid * 64) * 4], 16, 0, 0);
        }
    };

    float4 acc = make_float4(0.f, 0.f, 0.f, 0.f);

    auto COMP = [&](int s) {
        const float* xsl = &slots[s][XOFF + c * 116 + px0];
        float4 x0 = ld4(xsl), x1 = ld4(xsl + 4), x2 = ld4(xsl + 8),
               x3 = ld4(xsl + 12), x4 = ld4(xsl + 16), x5 = ld4(xsl + 20);
        float xv[24] = {x0.x,x0.y,x0.z,x0.w, x1.x,x1.y,x1.z,x1.w,
                        x2.x,x2.y,x2.z,x2.w, x3.x,x3.y,x3.z,x3.w,
                        x4.x,x4.y,x4.z,x4.w, x5.x,x5.y,x5.z,x5.w};
        const float* ksl = &slots[s][px0];
        #pragma unroll
        for (int kw = 0; kw < 19; ++kw) {
            float4 k = ld4(ksl + kw * 64);
            acc.x = fmaf(xv[kw + 0], k.x, acc.x);
            acc.y = fmaf(xv[kw + 1], k.y, acc.y);
            acc.z = fmaf(xv[kw + 2], k.z, acc.z);
            acc.w = fmaf(xv[kw + 3], k.w, acc.w);
        }
    };

    // Prologue: stage steps 0..2 (9 loads/wave outstanding).
    STAGE(0, 0); STAGE(1, 1); STAGE(2, 2);

#define STEPM(kh, NW)                                                         \
    asm volatile("s_waitcnt vmcnt(" #NW ")" ::: "memory");                    \
    __builtin_amdgcn_sched_barrier(0);                                        \
    __builtin_amdgcn_s_barrier();                                             \
    __builtin_amdgcn_sched_barrier(0);                                        \
    if ((kh) + 3 < 19) STAGE((kh) + 3, ((kh) + 3) & 3);                       \
    __builtin_amdgcn_sched_barrier(0);                                        \
    COMP((kh) & 3);                                                           \
    __builtin_amdgcn_sched_barrier(0);

    STEPM(0, 6)  STEPM(1, 6)  STEPM(2, 6)  STEPM(3, 6)  STEPM(4, 6)
    STEPM(5, 6)  STEPM(6, 6)  STEPM(7, 6)  STEPM(8, 6)  STEPM(9, 6)
    STEPM(10, 6) STEPM(11, 6) STEPM(12, 6) STEPM(13, 6) STEPM(14, 6)
    STEPM(15, 6) STEPM(16, 6) STEPM(17, 3) STEPM(18, 0)
#undef STEPM

    float* yp = ypad + ((size_t)(b * C + c) * YR + (h + 1)) * YS + (w0 + px0 + 4);
    *(float4*)yp = acc;
}

// ===========================================================================
// conv1: 3x3 conv (pad 1) + exact GELU -> xpad. Thread = 1 px x 2 oc.
// Block = 128 px x 2 oc-pairs; grid = ocq4 x h128 x b2 = 1024 (16 waves/CU).
// Taps coalesced (lane = px), shared across the 2 oc; weights LDS broadcast.
// ===========================================================================
__global__ __launch_bounds__(256) void conv1_gelu(
    const float* __restrict__ in, const float* __restrict__ w1,
    const float* __restrict__ b1, float* __restrict__ xpad)
{
    __shared__ float ws[2304];
    __shared__ float bs[16];
    for (int i = threadIdx.x; i < 2304; i += 256) ws[i] = w1[i];
    if (threadIdx.x < 16) bs[threadIdx.x] = b1[threadIdx.x];
    __syncthreads();

    int px  = threadIdx.x & 127;
    int opg = threadIdx.x >> 7;          // wave-uniform
    int blk = blockIdx.x;                // 1024 = ocq4 x h128 x b2
    int ocq = blk & 3;
    int h   = (blk >> 2) & 127;
    int b   = blk >> 9;
    int oc0 = ocq * 4 + opg * 2;

    const float* inb = in + (size_t)b * C * HW;
    bool hm = (h > 0), hp = (h < 127), wm = (px > 0), wp = (px < 127);

    float a0 = 0.f, a1 = 0.f;
    #pragma unroll
    for (int ic = 0; ic < 16; ++ic) {
        const float* p0 = inb + (size_t)ic * HW + (size_t)h * W + px;
        float t0 = (hm && wm) ? p0[-W - 1] : 0.f;
        float t1 = hm         ? p0[-W]     : 0.f;
        float t2 = (hm && wp) ? p0[-W + 1] : 0.f;
        float t3 = wm         ? p0[-1]     : 0.f;
        float t4 =              p0[0];
        float t5 = wp         ? p0[1]      : 0.f;
        float t6 = (hp && wm) ? p0[W - 1]  : 0.f;
        float t7 = hp         ? p0[W]      : 0.f;
        float t8 = (hp && wp) ? p0[W + 1]  : 0.f;
        #pragma unroll
        for (int j = 0; j < 2; ++j) {
            const float* wp9 = ws + (oc0 + j) * 144 + ic * 9;
            float s = fmaf(wp9[0], t0, fmaf(wp9[1], t1, fmaf(wp9[2], t2,
                      fmaf(wp9[3], t3, fmaf(wp9[4], t4, fmaf(wp9[5], t5,
                      fmaf(wp9[6], t6, fmaf(wp9[7], t7, wp9[8] * t8))))))));
            if (j == 0) a0 += s; else a1 += s;
        }
    }

    float* xp = xpad + ((size_t)(b * C + oc0) * XR + (h + 9)) * XS + (px + 9);
    float v;
    v = a0 + bs[oc0 + 0]; xp[0]   = 0.5f * v * (1.0f + erff(v * 0.70710678f));
    v = a1 + bs[oc0 + 1]; xp[XCH] = 0.5f * v * (1.0f + erff(v * 0.70710678f));
}

// ===========================================================================
// conv2: 3x3 conv (pad 1) + sigmoid -> out. Same geometry; padded y input so
// taps are unconditional.
// ===========================================================================
__global__ __launch_bounds__(256) void conv2_sig(
    const float* __restrict__ ypad, const float* __restrict__ w2,
    const float* __restrict__ b2, float* __restrict__ out)
{
    __shared__ float ws[2304];
    __shared__ float bs[16];
    for (int i = threadIdx.x; i < 2304; i += 256) ws[i] = w2[i];
    if (threadIdx.x < 16) bs[threadIdx.x] = b2[threadIdx.x];
    __syncthreads();

    int px  = threadIdx.x & 127;
    int opg = threadIdx.x >> 7;
    int blk = blockIdx.x;                // 1024 = ocq4 x h128 x b2
    int ocq = blk & 3;
    int h   = (blk >> 2) & 127;
    int b   = blk >> 9;
    int oc0 = ocq * 4 + opg * 2;

    float a0 = 0.f, a1 = 0.f;
    #pragma unroll
    for (int ic = 0; ic < 16; ++ic) {
        const float* p0 = ypad + ((size_t)(b * C + ic) * YR + (h + 1)) * YS + (px + 4);
        float t0 = p0[-YS - 1], t1 = p0[-YS], t2 = p0[-YS + 1];
        float t3 = p0[-1],      t4 = p0[0],   t5 = p0[1];
        float t6 = p0[YS - 1],  t7 = p0[YS],  t8 = p0[YS + 1];
        #pragma unroll
        for (int j = 0; j < 2; ++j) {
            const float* wp9 = ws + (oc0 + j) * 144 + ic * 9;
            float s = fmaf(wp9[0], t0, fmaf(wp9[1], t1, fmaf(wp9[2], t2,
                      fmaf(wp9[3], t3, fmaf(wp9[4], t4, fmaf(wp9[5], t5,
                      fmaf(wp9[6], t6, fmaf(wp9[7], t7, wp9[8] * t8))))))));
            if (j == 0) a0 += s; else a1 += s;
        }
    }

    float* op = out + ((size_t)(b * C + oc0) * H + h) * W + px;
    float v;
    v = a0 + bs[oc0 + 0]; op[0]  = 1.0f / (1.0f + expf(-v));
    v = a1 + bs[oc0 + 1]; op[HW] = 1.0f / (1.0f + expf(-v));
}

// ---------------------------------------------------------------------------
extern "C" void kernel_launch(void* const* d_in, const int* in_sizes, int n_in,
                              void* d_out, int out_size, void* d_ws, size_t ws_size,
                              hipStream_t stream)
{
    const float* input  = (const float*)d_in[0];
    const float* kernel = (const float*)d_in[1];
    const float* w1     = (const float*)d_in[2];
    const float* b1     = (const float*)d_in[3];
    const float* w2     = (const float*)d_in[4];
    const float* b2     = (const float*)d_in[5];
    float* out = (float*)d_out;

    float* xpad = (float*)d_ws;
    float* ypad = xpad + XPAD_ELEMS;

    hipMemsetAsync(d_ws, 0, (XPAD_ELEMS + YPAD_ELEMS) * sizeof(float), stream);

    conv1_gelu<<<1024, 256, 0, stream>>>(input, w1, b1, xpad);
    kpn19<<<512, 256, 0, stream>>>(xpad, kernel, ypad);
    conv2_sig<<<1024, 256, 0, stream>>>(ypad, w2, b2, out);
}